// Round 1
// baseline (1727.815 us; speedup 1.0000x reference)
//
#include <hip/hip_runtime.h>
#include <hip/hip_bf16.h>
#include <cstdint>
#include <cstddef>

#define H 256
#define L 128
#define B 512
#define LEVELS 7
#define BH (B * H)

// d_out layout (flat f32 element offsets), return order:
// root[B,H], internal_states[255,B,H], internal_mask[255,B],
// leaves[L,B,H], leaves_aux[L,B,H], leaves_mask[L,B]
#define OFF_ROOT 0
#define OFF_INT (B * H)                  // 131072
#define OFF_IMASK (OFF_INT + 255 * BH)   // 33554432
#define OFF_LEAVES (OFF_IMASK + 255 * B) // 33684992
#define OFF_LAUX (OFF_LEAVES + L * BH)   // 50462208
#define OFF_LMASK (OFF_LAUX + L * BH)    // 67239424

// Post-order position of node (level, j) in the 255-node complete tree.
// Subtree sizes skipped for each "right child" step on the path, plus own
// subtree size - 1. Verified against the reference recursion for small trees.
__device__ __forceinline__ int postorder_pos(int level, int j) {
    int start = 0;
    for (int k = level; k <= LEVELS; ++k) {
        if ((j >> (k - level)) & 1) start += (2 << k) - 1; // 2^(k+1)-1
    }
    return start + (2 << level) - 2; // + 2^(level+1) - 2
}

__device__ __forceinline__ float sigm(float x) { return 1.0f / (1.0f + __expf(-x)); }

// Gather: leaves = emb[tok], leaves_aux = emb_aux[tok]; leaf h also goes to
// its post-order slot in internal_states (per_level_h includes level 0).
__global__ __launch_bounds__(256) void gather_kernel(
    const int* __restrict__ tok, const float* __restrict__ emb,
    const float* __restrict__ emb_aux, float* __restrict__ out) {
    int row = blockIdx.x * 4 + (threadIdx.x >> 6); // row in [0, L*B)
    int f4i = threadIdx.x & 63;                    // 64 float4 per 256-col row
    int l = row >> 9, b = row & 511;
    int t = tok[row];
    float4 e = reinterpret_cast<const float4*>(emb + (size_t)t * H)[f4i];
    float4 ea = reinterpret_cast<const float4*>(emb_aux + (size_t)t * H)[f4i];
    reinterpret_cast<float4*>(out + OFF_LEAVES)[(size_t)row * 64 + f4i] = e;
    reinterpret_cast<float4*>(out + OFF_LAUX)[(size_t)row * 64 + f4i] = ea;
    int pp = postorder_pos(0, l);
    reinterpret_cast<float4*>(out + OFF_INT + (size_t)pp * BH + (size_t)b * H)[f4i] = e;
}

__global__ void mask_kernel(float* __restrict__ out) {
    int i = blockIdx.x * 256 + threadIdx.x;
    if (i < 255 * B) out[OFF_IMASK + i] = 1.0f;
    if (i < L * B) out[OFF_LMASK + i] = 1.0f;
}

// Fused GEMM + LSTM gates for one tree level.
// Block tile: TM=64 rows (one pair p, 64 batch rows) x TH=32 hidden cols
// (=160 gate cols: all 5 gates resident -> gates fuse in registers).
#define TM 64
#define TH 32
#define KB 32
#define APAD 36 // 144B row stride: 16B-aligned b128, banks spread
#define WPAD 36

__global__ __launch_bounds__(256) void lstm_level_kernel(
    const float* __restrict__ W, const float* __restrict__ bias,
    const float* __restrict__ c_prev, float* __restrict__ c_out,
    float* __restrict__ out, int level) {
    __shared__ float As[TM][APAD];
    __shared__ float Ws[5 * TH][WPAD]; // k-transposed: Ws[gatecol][k]

    const int tid = threadIdx.x;
    const int tx = tid & 15, ty = tid >> 4;
    const int r0 = blockIdx.x * TM; // global row = p*B + b
    const int p = r0 / B;
    const int b0 = r0 % B;
    const int hc0 = blockIdx.y * TH;

    const float* __restrict__ hL =
        out + OFF_INT + (size_t)postorder_pos(level - 1, 2 * p) * BH;
    const float* __restrict__ hR =
        out + OFF_INT + (size_t)postorder_pos(level - 1, 2 * p + 1) * BH;

    // acc[i][j]: row b0+ty+16i, gate col cc = tx+16j (gate=j>>1, hc=hc0+tx+16*(j&1))
    float acc[4][10];
#pragma unroll
    for (int i = 0; i < 4; ++i)
#pragma unroll
        for (int j = 0; j < 10; ++j)
            acc[i][j] = bias[(j >> 1) * H + hc0 + tx + 16 * (j & 1)];

    for (int kb = 0; kb < 512 / KB; ++kb) {
        const float* hsrc = (kb < 8) ? hL : hR; // A = [hL | hR]
        const int colbase = (kb & 7) * KB;
        // stage A tile: 64 rows x 32 k = 512 float4, 2 per thread
#pragma unroll
        for (int it = 0; it < 2; ++it) {
            int q = tid + 256 * it;
            int rr = q >> 3, f4i = q & 7;
            float4 v = *reinterpret_cast<const float4*>(
                hsrc + (size_t)(b0 + rr) * H + colbase + f4i * 4);
            *reinterpret_cast<float4*>(&As[rr][f4i * 4]) = v;
        }
        // stage W tile k-transposed: 32 k x 160 cols = 1280 float4, 5 per thread
#pragma unroll
        for (int it = 0; it < 5; ++it) {
            int q = tid + 256 * it;
            int kk = q / 40;
            int rem = q - kk * 40;
            int seg = rem >> 3, f4i = rem & 7;
            float4 v = *reinterpret_cast<const float4*>(
                W + (size_t)(kb * KB + kk) * 1280 + seg * H + hc0 + f4i * 4);
            int cc = seg * 32 + f4i * 4;
            Ws[cc + 0][kk] = v.x;
            Ws[cc + 1][kk] = v.y;
            Ws[cc + 2][kk] = v.z;
            Ws[cc + 3][kk] = v.w;
        }
        __syncthreads();
#pragma unroll
        for (int k4 = 0; k4 < KB; k4 += 4) {
            float4 a4[4], w4[10];
#pragma unroll
            for (int i = 0; i < 4; ++i)
                a4[i] = *reinterpret_cast<const float4*>(&As[ty + 16 * i][k4]);
#pragma unroll
            for (int j = 0; j < 10; ++j)
                w4[j] = *reinterpret_cast<const float4*>(&Ws[tx + 16 * j][k4]);
#pragma unroll
            for (int i = 0; i < 4; ++i)
#pragma unroll
                for (int j = 0; j < 10; ++j) {
                    acc[i][j] = fmaf(a4[i].x, w4[j].x, acc[i][j]);
                    acc[i][j] = fmaf(a4[i].y, w4[j].y, acc[i][j]);
                    acc[i][j] = fmaf(a4[i].z, w4[j].z, acc[i][j]);
                    acc[i][j] = fmaf(a4[i].w, w4[j].w, acc[i][j]);
                }
        }
        __syncthreads();
    }

    const int pout = postorder_pos(level, p);
    float* __restrict__ hout = out + OFF_INT + (size_t)pout * BH;
    const size_t cbase = (size_t)p * BH;

#pragma unroll
    for (int i = 0; i < 4; ++i) {
        const int b = b0 + ty + 16 * i;
#pragma unroll
        for (int s = 0; s < 2; ++s) {
            const int hc = hc0 + tx + 16 * s;
            float ig = acc[i][0 + s], f1 = acc[i][2 + s], f2 = acc[i][4 + s];
            float og = acc[i][6 + s], ug = acc[i][8 + s];
            float cL = 0.f, cR = 0.f;
            if (c_prev) {
                cL = c_prev[(size_t)(2 * p) * BH + (size_t)b * H + hc];
                cR = c_prev[(size_t)(2 * p + 1) * BH + (size_t)b * H + hc];
            }
            float c = sigm(ig) * tanhf(ug) + sigm(f1) * cL + sigm(f2) * cR;
            float h = sigm(og) * tanhf(c);
            c_out[cbase + (size_t)b * H + hc] = c;
            hout[(size_t)b * H + hc] = h;
            if (level == LEVELS) out[OFF_ROOT + (size_t)b * H + hc] = h;
        }
    }
}

extern "C" void kernel_launch(void* const* d_in, const int* in_sizes, int n_in,
                              void* d_out, int out_size, void* d_ws,
                              size_t ws_size, hipStream_t stream) {
    const int* tok = (const int*)d_in[0];
    const float* emb = (const float*)d_in[1];
    const float* emb_aux = (const float*)d_in[2];
    const float* W = (const float*)d_in[3];
    const float* bias = (const float*)d_in[4];
    float* out = (float*)d_out;
    // c ping-pong: 2 x 64*B*H f32 = 64 MiB of d_ws; fully written before read.
    float* cbuf0 = (float*)d_ws;
    float* cbuf1 = cbuf0 + (size_t)64 * BH;

    hipLaunchKernelGGL(gather_kernel, dim3(L * B / 4), dim3(256), 0, stream,
                       tok, emb, emb_aux, out);
    hipLaunchKernelGGL(mask_kernel, dim3((255 * B + 255) / 256), dim3(256), 0,
                       stream, out);

    for (int level = 1; level <= LEVELS; ++level) {
        int n = L >> level; // nodes at this level
        float* c_out = ((level - 1) & 1) ? cbuf1 : cbuf0;
        const float* c_prev =
            (level == 1) ? nullptr : ((level & 1) ? cbuf1 : cbuf0);
        dim3 grid(n * (B / TM), H / TH);
        hipLaunchKernelGGL(lstm_level_kernel, grid, dim3(256), 0, stream, W,
                           bias, c_prev, c_out, out, level);
    }
}

// Round 2
// 419.419 us; speedup vs baseline: 4.1195x; 4.1195x over previous
//
#include <hip/hip_runtime.h>
#include <hip/hip_bf16.h>
#include <cstdint>
#include <cstddef>

#define H 256
#define L 128
#define B 512
#define LEVELS 7
#define BH (B * H)

// d_out layout (flat f32 element offsets), return order:
// root[B,H], internal_states[255,B,H], internal_mask[255,B],
// leaves[L,B,H], leaves_aux[L,B,H], leaves_mask[L,B]
#define OFF_ROOT 0
#define OFF_INT (B * H)
#define OFF_IMASK (OFF_INT + 255 * BH)
#define OFF_LEAVES (OFF_IMASK + 255 * B)
#define OFF_LAUX (OFF_LEAVES + L * BH)
#define OFF_LMASK (OFF_LAUX + L * BH)

typedef unsigned short u16;
typedef __attribute__((ext_vector_type(8))) short short8;
typedef __attribute__((ext_vector_type(4))) float f32x4;

// Post-order position of node (level, j) in the 255-node complete tree.
__device__ __forceinline__ int postorder_pos(int level, int j) {
    int start = 0;
    for (int k = level; k <= LEVELS; ++k) {
        if ((j >> (k - level)) & 1) start += (2 << k) - 1;
    }
    return start + (2 << level) - 2;
}

__device__ __forceinline__ float sigm(float x) { return 1.0f / (1.0f + __expf(-x)); }

__device__ __forceinline__ u16 f2bf(float x) {
    __hip_bfloat16 b = __float2bfloat16(x);
    u16 u;
    __builtin_memcpy(&u, &b, 2);
    return u;
}
__device__ __forceinline__ float bfc(u16 u) {
    union { unsigned int ui; float f; } c;
    c.ui = ((unsigned int)u) << 16;
    return c.f;
}

__device__ __forceinline__ void gload16(const void* g, const void* l) {
    __builtin_amdgcn_global_load_lds(
        (const __attribute__((address_space(1))) void*)g,
        (__attribute__((address_space(3))) void*)l, 16, 0, 0);
}

// ---------------- gather / masks (unchanged from R1, passed) ----------------
__global__ __launch_bounds__(256) void gather_kernel(
    const int* __restrict__ tok, const float* __restrict__ emb,
    const float* __restrict__ emb_aux, float* __restrict__ out) {
    int row = blockIdx.x * 4 + (threadIdx.x >> 6);
    int f4i = threadIdx.x & 63;
    int l = row >> 9, b = row & 511;
    int t = tok[row];
    float4 e = reinterpret_cast<const float4*>(emb + (size_t)t * H)[f4i];
    float4 ea = reinterpret_cast<const float4*>(emb_aux + (size_t)t * H)[f4i];
    reinterpret_cast<float4*>(out + OFF_LEAVES)[(size_t)row * 64 + f4i] = e;
    reinterpret_cast<float4*>(out + OFF_LAUX)[(size_t)row * 64 + f4i] = ea;
    int pp = postorder_pos(0, l);
    reinterpret_cast<float4*>(out + OFF_INT + (size_t)pp * BH + (size_t)b * H)[f4i] = e;
}

__global__ void mask_kernel(float* __restrict__ out) {
    int i = blockIdx.x * 256 + threadIdx.x;
    if (i < 255 * B) out[OFF_IMASK + i] = 1.0f;
    if (i < L * B) out[OFF_LMASK + i] = 1.0f;
}

// ---------------- W pre-pack: split f32 W into hi/lo bf16 tiles ----------------
// Layout: [hcb=8][kb=16][cc=160][kk=32], cc = gate*32 + (hc-hcb*32).
// Each (hcb,kb) tile is 5120 contiguous bf16 (10 KiB), K-transposed so the
// 16x16x32 B-fragment read (8 consecutive k per lane) is one ds_read_b128.
__global__ __launch_bounds__(256) void wpack_kernel(const float* __restrict__ W,
                                                    u16* __restrict__ hi,
                                                    u16* __restrict__ lo) {
    int e = blockIdx.x * 256 + threadIdx.x; // 0 .. 655359
    int kk = e & 31;
    int idx2 = e >> 5;
    int cc = idx2 % 160;
    int t = idx2 / 160;
    int kb = t & 15, hcb = t >> 4;
    int k = kb * 32 + kk;
    int col = (cc >> 5) * 256 + hcb * 32 + (cc & 31);
    float x = W[(size_t)k * 1280 + col];
    u16 h = f2bf(x);
    float r = x - bfc(h);
    hi[e] = h;
    lo[e] = f2bf(r);
}

// ---------------- fused split-bf16 MFMA GEMM + LSTM gates ----------------
// Block: 256 thr (4 waves), tile BM=128 rows x 32 hc (=160 gate cols), BK=32.
// Waves split along M (32 rows each, all 160 cols) -> register gate epilogue.
__global__ __launch_bounds__(256, 2) void lstm_level_kernel(
    const u16* __restrict__ Whi, const u16* __restrict__ Wlo,
    const float* __restrict__ bias, const float* __restrict__ c_prev,
    float* __restrict__ c_out, float* __restrict__ out, int level) {
    __shared__ __align__(16) u16 Ahi[128][32];
    __shared__ __align__(16) u16 Alo[128][32];
    __shared__ __align__(16) u16 Wst[2][160 * 32]; // [hi/lo][cc*32+kk]

    const int tid = threadIdx.x;
    const int p = blockIdx.x >> 2;
    const int b0 = (blockIdx.x & 3) * 128;
    const int hcb = blockIdx.y;
    const int hc0 = hcb * 32;

    const int lane = tid & 63;
    const int wm = tid >> 6;   // wave id: rows 32*wm .. 32*wm+31
    const int r15 = lane & 15;
    const int kq = lane >> 4;  // 0..3

    const float* __restrict__ hL =
        out + OFF_INT + (size_t)postorder_pos(level - 1, 2 * p) * BH;
    const float* __restrict__ hR =
        out + OFF_INT + (size_t)postorder_pos(level - 1, 2 * p + 1) * BH;

    // acc[mi][ni]: rows 32*wm+16*mi+{4*kq+r}, gate col cc = ni*16 + r15
    f32x4 acc[2][10];
#pragma unroll
    for (int ni = 0; ni < 10; ++ni) {
        float bv = bias[(ni >> 1) * H + hc0 + (ni & 1) * 16 + r15];
        f32x4 v = {bv, bv, bv, bv};
        acc[0][ni] = v;
        acc[1][ni] = v;
    }

    for (int kb = 0; kb < 16; ++kb) {
        // --- async W tile stage (linear: pre-packed layout) ---
        const u16* gH = Whi + (size_t)(hcb * 16 + kb) * 5120;
        const u16* gL = Wlo + (size_t)(hcb * 16 + kb) * 5120;
#pragma unroll
        for (int it = 0; it < 3; ++it) {
            int chunk = tid + it * 256;            // 16B units, 640 total
            int wbase = (tid & 192) + it * 256;    // wave-uniform LDS base
            if (chunk < 640) {
                gload16(gH + chunk * 8, &Wst[0][wbase * 8]);
                gload16(gL + chunk * 8, &Wst[1][wbase * 8]);
            }
        }
        // --- A tile stage: read child h (f32), split into hi/lo bf16 ---
        const float* hsrc = (kb < 8) ? hL : hR;
        const int kc0 = (kb & 7) * 32;
#pragma unroll
        for (int it = 0; it < 2; ++it) {
            int q = tid + it * 256;   // 0..511
            int rr = q >> 2, kg = q & 3;
            const float* src = hsrc + (size_t)(b0 + rr) * H + kc0 + kg * 8;
            float4 v0 = *reinterpret_cast<const float4*>(src);
            float4 v1 = *reinterpret_cast<const float4*>(src + 4);
            float xs[8] = {v0.x, v0.y, v0.z, v0.w, v1.x, v1.y, v1.z, v1.w};
            short8 hv, lv;
#pragma unroll
            for (int i2 = 0; i2 < 8; ++i2) {
                u16 hu = f2bf(xs[i2]);
                float rres = xs[i2] - bfc(hu);
                hv[i2] = (short)hu;
                lv[i2] = (short)f2bf(rres);
            }
            *reinterpret_cast<short8*>(&Ahi[rr][kg * 8]) = hv;
            *reinterpret_cast<short8*>(&Alo[rr][kg * 8]) = lv;
        }
        __syncthreads();

        // --- MFMA: acc += Ahi*Whi + Alo*Whi + Ahi*Wlo ---
        short8 ah0 = *reinterpret_cast<const short8*>(&Ahi[32 * wm + r15][8 * kq]);
        short8 ah1 = *reinterpret_cast<const short8*>(&Ahi[32 * wm + 16 + r15][8 * kq]);
        short8 al0 = *reinterpret_cast<const short8*>(&Alo[32 * wm + r15][8 * kq]);
        short8 al1 = *reinterpret_cast<const short8*>(&Alo[32 * wm + 16 + r15][8 * kq]);
#pragma unroll
        for (int ni = 0; ni < 10; ++ni) {
            const int wo = (ni * 16 + r15) * 32 + 8 * kq;
            short8 bh = *reinterpret_cast<const short8*>(&Wst[0][wo]);
            short8 bl = *reinterpret_cast<const short8*>(&Wst[1][wo]);
            acc[0][ni] = __builtin_amdgcn_mfma_f32_16x16x32_bf16(ah0, bh, acc[0][ni], 0, 0, 0);
            acc[1][ni] = __builtin_amdgcn_mfma_f32_16x16x32_bf16(ah1, bh, acc[1][ni], 0, 0, 0);
            acc[0][ni] = __builtin_amdgcn_mfma_f32_16x16x32_bf16(al0, bh, acc[0][ni], 0, 0, 0);
            acc[1][ni] = __builtin_amdgcn_mfma_f32_16x16x32_bf16(al1, bh, acc[1][ni], 0, 0, 0);
            acc[0][ni] = __builtin_amdgcn_mfma_f32_16x16x32_bf16(ah0, bl, acc[0][ni], 0, 0, 0);
            acc[1][ni] = __builtin_amdgcn_mfma_f32_16x16x32_bf16(ah1, bl, acc[1][ni], 0, 0, 0);
        }
        __syncthreads();
    }

    // --- epilogue: gates in registers -> c, h ---
    const int pout = postorder_pos(level, p);
    float* __restrict__ hout = out + OFF_INT + (size_t)pout * BH;
    const float* cLb = c_prev ? c_prev + (size_t)(2 * p) * BH : nullptr;
    const float* cRb = c_prev ? c_prev + (size_t)(2 * p + 1) * BH : nullptr;
    float* __restrict__ cob = c_out + (size_t)p * BH;

#pragma unroll
    for (int mi = 0; mi < 2; ++mi) {
#pragma unroll
        for (int r = 0; r < 4; ++r) {
            const int b = b0 + 32 * wm + 16 * mi + 4 * kq + r;
#pragma unroll
            for (int s = 0; s < 2; ++s) {
                const int hc = hc0 + s * 16 + r15;
                float ig = acc[mi][0 + s][r];
                float f1 = acc[mi][2 + s][r];
                float f2 = acc[mi][4 + s][r];
                float og = acc[mi][6 + s][r];
                float ug = acc[mi][8 + s][r];
                float cl = 0.f, cr = 0.f;
                if (c_prev) {
                    cl = cLb[(size_t)b * H + hc];
                    cr = cRb[(size_t)b * H + hc];
                }
                float c = sigm(ig) * tanhf(ug) + sigm(f1) * cl + sigm(f2) * cr;
                float hval = sigm(og) * tanhf(c);
                cob[(size_t)b * H + hc] = c;
                hout[(size_t)b * H + hc] = hval;
                if (level == LEVELS) out[OFF_ROOT + (size_t)b * H + hc] = hval;
            }
        }
    }
}

extern "C" void kernel_launch(void* const* d_in, const int* in_sizes, int n_in,
                              void* d_out, int out_size, void* d_ws,
                              size_t ws_size, hipStream_t stream) {
    const int* tok = (const int*)d_in[0];
    const float* emb = (const float*)d_in[1];
    const float* emb_aux = (const float*)d_in[2];
    const float* W = (const float*)d_in[3];
    const float* bias = (const float*)d_in[4];
    float* out = (float*)d_out;

    // ws layout: cbuf0 (64*BH f32) | cbuf1 (64*BH f32) | Whi | Wlo (bf16 packs)
    float* cbuf0 = (float*)d_ws;
    float* cbuf1 = cbuf0 + (size_t)64 * BH;
    u16* wphi = (u16*)(cbuf0 + (size_t)128 * BH);
    u16* wplo = wphi + (size_t)8 * 16 * 160 * 32;

    hipLaunchKernelGGL(wpack_kernel, dim3(2560), dim3(256), 0, stream, W, wphi,
                       wplo);
    hipLaunchKernelGGL(gather_kernel, dim3(L * B / 4), dim3(256), 0, stream,
                       tok, emb, emb_aux, out);
    hipLaunchKernelGGL(mask_kernel, dim3((255 * B + 255) / 256), dim3(256), 0,
                       stream, out);

    for (int level = 1; level <= LEVELS; ++level) {
        int n = L >> level;
        float* c_out = ((level - 1) & 1) ? cbuf1 : cbuf0;
        const float* c_prev =
            (level == 1) ? nullptr : ((level & 1) ? cbuf1 : cbuf0);
        dim3 grid(n * 4, 8);
        hipLaunchKernelGGL(lstm_level_kernel, grid, dim3(256), 0, stream, wphi,
                           wplo, bias, c_prev, c_out, out, level);
    }
}